// Round 11
// baseline (3688.600 us; speedup 1.0000x reference)
//
#include <hip/hip_runtime.h>
#include <hip/hip_bf16.h>

#define T_STEPS 2048
#define NB      64
#define IN_DIM  300
#define HID     512

typedef __attribute__((ext_vector_type(8))) short short8;   // 8 bf16 (4 VGPR)
typedef __attribute__((ext_vector_type(4))) float f32x4;    // MFMA f32 accum
typedef __attribute__((ext_vector_type(4))) int   i32x4;    // MFMA i8 frag/accum

#define USCALE 369.33000f                // 2*log2(e)*128 (table fixed-point)

static __device__ __forceinline__ unsigned short f2bf(float x) {
    unsigned int u = __float_as_uint(x);
    u = u + 0x7FFFu + ((u >> 16) & 1u);          // round-to-nearest-even
    return (unsigned short)(u >> 16);
}
static __device__ __forceinline__ unsigned cvtpk(float lo, float hi) {
    unsigned r;
    asm("v_cvt_pk_bf16_f32 %0, %1, %2" : "=v"(r) : "v"(lo), "v"(hi));
    return r;
}

// tanh+int8-quantize 4 values via LDS table (see R10). zero transcendentals.
static __device__ __forceinline__ unsigned tq4t(const i32x4 a, const f32x4 s,
                                                unsigned w0, unsigned w1,
                                                const unsigned char* tab) {
    unsigned q[4];
    #pragma unroll
    for (int r = 0; r < 4; ++r) {
        const unsigned word = (r < 2) ? w0 : w1;
        const float uf = __uint_as_float((r & 1) ? (word & 0xFFFF0000u) : (word << 16));
        const float xi = fmaf((float)a[r], s[r], uf) + 12582912.f;   // 2^23*1.5
        const float xc = __builtin_amdgcn_fmed3f(xi, 12580864.f, 12584959.f);
        q[r] = tab[__float_as_uint(xc) & 0xFFFu];                    // ds_read_u8
    }
    return __builtin_amdgcn_perm(
        __builtin_amdgcn_perm(q[3], q[2], 0x0C0C0400u),
        __builtin_amdgcn_perm(q[1], q[0], 0x0C0C0400u), 0x05040100u);
}

// ---------------------------------------------------------------------------
// Kernel 1: U = bf16( (x_t W_ih^T + b_ih + b_hh) * 2log2e*128 ), rec-lane
// order: U3[t][g(4)][wv(8)][lane(64)][c4(4)][r(4)]   (unchanged from R10)
// ---------------------------------------------------------------------------
__global__ __launch_bounds__(256, 4) void u_gemm(
    const float* __restrict__ X, const float* __restrict__ Wih,
    const float* __restrict__ bih, const float* __restrict__ bhh,
    unsigned short* __restrict__ U3)
{
    __shared__ unsigned short As[64 * 160];   // X rows (batch m)
    __shared__ unsigned short Bs[64 * 160];   // Wih rows (j)
    const int tid = threadIdx.x;
    const int m0 = (blockIdx.x >> 3) * 64, n0 = (blockIdx.x & 7) * 64;
    const int w = tid >> 6, l = tid & 63;
    const int lq = l >> 4, lr = l & 15;

    const f32x4 zv = {0.f, 0.f, 0.f, 0.f};
    f32x4 acc[2][2] = {{zv, zv}, {zv, zv}};   // [jt][mt]

    for (int kh = 0; kh < 2; ++kh) {
        const int kbase = kh * 160;
        __syncthreads();
        for (int i = tid; i < 64 * 40; i += 256) {
            const int r = i / 40, q = i - r * 40;
            const int kg = kbase + q * 4;
            unsigned int a0 = 0, a1 = 0, b0 = 0, b1 = 0;
            if (kg + 4 <= IN_DIM) {
                const float4 v = *reinterpret_cast<const float4*>(X + (size_t)(m0 + r) * IN_DIM + kg);
                a0 = (unsigned)f2bf(v.x) | ((unsigned)f2bf(v.y) << 16);
                a1 = (unsigned)f2bf(v.z) | ((unsigned)f2bf(v.w) << 16);
                const float4 u = *reinterpret_cast<const float4*>(Wih + (size_t)(n0 + r) * IN_DIM + kg);
                b0 = (unsigned)f2bf(u.x) | ((unsigned)f2bf(u.y) << 16);
                b1 = (unsigned)f2bf(u.z) | ((unsigned)f2bf(u.w) << 16);
            }
            int byte = r * 320 + q * 8; byte ^= ((r & 7) << 4);
            *reinterpret_cast<uint2*>(reinterpret_cast<char*>(As) + byte) = make_uint2(a0, a1);
            *reinterpret_cast<uint2*>(reinterpret_cast<char*>(Bs) + byte) = make_uint2(b0, b1);
        }
        __syncthreads();
        #pragma unroll
        for (int kc = 0; kc < 5; ++kc) {
            const int koff = kc * 64 + lq * 16;
            short8 xa[2], wb[2];
            #pragma unroll
            for (int mt = 0; mt < 2; ++mt) {
                const int row = (w >> 1) * 32 + mt * 16 + lr;       // X row (m)
                int abyte = row * 320 + koff; abyte ^= ((row & 7) << 4);
                xa[mt] = *reinterpret_cast<const short8*>(reinterpret_cast<const char*>(As) + abyte);
                const int jrow = (w & 1) * 32 + mt * 16 + lr;       // W row (j)
                int bbyte = jrow * 320 + koff; bbyte ^= ((jrow & 7) << 4);
                wb[mt] = *reinterpret_cast<const short8*>(reinterpret_cast<const char*>(Bs) + bbyte);
            }
            #pragma unroll
            for (int jt = 0; jt < 2; ++jt)
                #pragma unroll
                for (int mt = 0; mt < 2; ++mt)
                    acc[jt][mt] = __builtin_amdgcn_mfma_f32_16x16x32_bf16(
                        wb[jt], xa[mt], acc[jt][mt], 0, 0, 0);
        }
    }
    const int t = blockIdx.x >> 3;
    #pragma unroll
    for (int jt = 0; jt < 2; ++jt) {
        const int jb = n0 + (w & 1) * 32 + jt * 16 + 4 * lq;        // 4 consecutive j
        const float4 b1v = *reinterpret_cast<const float4*>(bih + jb);
        const float4 b2v = *reinterpret_cast<const float4*>(bhh + jb);
        const float4 bv = {(b1v.x + b2v.x) * USCALE, (b1v.y + b2v.y) * USCALE,
                           (b1v.z + b2v.z) * USCALE, (b1v.w + b2v.w) * USCALE};
        const int jtg = jb >> 4;
        const int wv2 = jtg >> 2, cc = jtg & 3;
        #pragma unroll
        for (int mt = 0; mt < 2; ++mt) {
            const int b = (w >> 1) * 32 + mt * 16 + lr;             // batch row
            const int g = b >> 4, lrr = b & 15;
            const f32x4 a = acc[jt][mt];
            uint2 p;
            p.x = cvtpk(fmaf(a[0], USCALE, bv.x), fmaf(a[1], USCALE, bv.y));
            p.y = cvtpk(fmaf(a[2], USCALE, bv.z), fmaf(a[3], USCALE, bv.w));
            const size_t sidx = ((((size_t)t * 4 + g) * 8 + wv2) * 64 + (lq * 16 + lrr)) * 16 + cc * 4;
            *reinterpret_cast<uint2*>(U3 + sidx) = p;
        }
    }
}

// ---------------------------------------------------------------------------
// Kernel 2: int8 recurrence, ONE WAVE PER SIMD. 4 blocks x 256 thr (4 waves).
// Wave w owns j-tiles 8w..8w+7: wq[8][8] = 256 VGPR stationary (legal at
// 1 wave/SIMD; no spill through ~450 per m08). 64 MFMA + 32-value table-tq
// per wave per step, chains PAIRED (2 indep accumulators cover MFMA latency),
// tq of finished chains sourced between later pairs -> single-wave in-order
// issue fills matrix-pipe gaps with VALU. 1 barrier/step, parity-dbuf h.
// ---------------------------------------------------------------------------
__global__ __launch_bounds__(256) __attribute__((amdgpu_waves_per_eu(1, 1)))
void rnn_rec(const float* __restrict__ Whh, const unsigned short* __restrict__ U3,
             float* __restrict__ out)
{
    const int g = blockIdx.x;                // 0..3
    const int tid = threadIdx.x;
    const int w = tid >> 6, l = tid & 63;    // w in 0..3
    const int lq = l >> 4, lr = l & 15;

    __shared__ char h8[2 * 16 * 512];        // [parity][m][k] swizzled
    __shared__ float wsc_lds[512];           // per-j scale (pre-scaled)
    __shared__ unsigned char ttab[4096];     // tanh+quant table (2's-compl idx)

    // ---- one-time: tanh table ----
    for (int i = tid; i < 4096; i += 256) {
        const int v = (i < 2048) ? i : i - 4096;
        const float x2 = (float)v * 0.0078125f;          // /128
        const float e = __builtin_amdgcn_exp2f(x2);
        const float th = (e - 1.f) / (e + 1.f);          // tanh(x2*ln2/2)
        ttab[i] = (unsigned char)(int)rintf(127.f * th);
    }

    // ---- one-time: quantize W to registers (8 tiles/wave, static idx) ----
    i32x4 wq[8][8];
    #pragma unroll
    for (int c = 0; c < 8; ++c) {
        const float* wr = Whh + (size_t)((8 * w + c) * 16 + lr) * HID;
        float amax = 0.f;
        #pragma unroll
        for (int kt = 0; kt < 8; ++kt) {
            const int k0 = kt * 64 + lq * 16;
            #pragma unroll
            for (int q4 = 0; q4 < 4; ++q4) {
                const float4 v = *reinterpret_cast<const float4*>(wr + k0 + q4 * 4);
                amax = fmaxf(amax, fmaxf(fmaxf(fabsf(v.x), fabsf(v.y)),
                                         fmaxf(fabsf(v.z), fabsf(v.w))));
            }
        }
        amax = fmaxf(amax, __shfl_xor(amax, 16));
        amax = fmaxf(amax, __shfl_xor(amax, 32));    // full-row max
        const float inv = 127.f / amax;
        #pragma unroll
        for (int kt = 0; kt < 8; ++kt) {
            const int k0 = kt * 64 + lq * 16;
            i32x4 pk;
            #pragma unroll
            for (int q4 = 0; q4 < 4; ++q4) {
                const float4 v = *reinterpret_cast<const float4*>(wr + k0 + q4 * 4);
                const int q0 = (int)rintf(v.x * inv), q1 = (int)rintf(v.y * inv);
                const int q2 = (int)rintf(v.z * inv), q3 = (int)rintf(v.w * inv);
                pk[q4] = (q0 & 255) | ((q1 & 255) << 8) | ((q2 & 255) << 16) | (q3 << 24);
            }
            wq[c][kt] = pk;
        }
        if (lq == 0)
            wsc_lds[(8 * w + c) * 16 + lr] = amax * (USCALE / 16129.f);
    }
    // ---- h0 = 0 (both parities) ----
    for (int i = tid * 32; i < 2 * 16 * 512; i += 256 * 32) {
        *reinterpret_cast<uint4*>(h8 + i) = make_uint4(0, 0, 0, 0);
        *reinterpret_cast<uint4*>(h8 + i + 16) = make_uint4(0, 0, 0, 0);
    }
    __syncthreads();

    // per-lane D-column scales: j = (8w+c)*16 + 4lq + r
    f32x4 sc2[8];
    #pragma unroll
    for (int c = 0; c < 8; ++c) {
        const float4 s = *reinterpret_cast<const float4*>(&wsc_lds[(8 * w + c) * 16 + 4 * lq]);
        sc2[c] = f32x4{s.x, s.y, s.z, s.w};
    }

    const int swz = (lr & 7) << 4;
    const int rrow = lr * 512;
    const int lq16 = lq * 16;
    int wrA[8];
    #pragma unroll
    for (int c = 0; c < 8; ++c)
        wrA[c] = rrow + ((((8 * w + c) * 16) + 4 * lq) ^ swz);

    // U: this wave needs old-wv {2w, 2w+1}: uint4 at +0,+8 and +1024,+1032
    const unsigned short* ub = U3 + ((size_t)(g * 8 + 2 * w) * 64 + l) * 16;
    uint4 uXa = *reinterpret_cast<const uint4*>(ub);
    uint4 uXb = *reinterpret_cast<const uint4*>(ub + 8);
    uint4 uXc = *reinterpret_cast<const uint4*>(ub + 1024);
    uint4 uXd = *reinterpret_cast<const uint4*>(ub + 1032);
    const unsigned short* uptr = ub + 32768;
    uint4 uYa, uYb, uYc, uYd;

#define MFMA_I8(W_, H_, A_) __builtin_amdgcn_mfma_i32_16x16x64_i8(W_, H_, A_, 0, 0, 0)
#define PAIR_KT(AA, AB, CA_, CB_, KT)                                          \
    AA = MFMA_I8(wq[CA_][KT], hv[KT], AA); AB = MFMA_I8(wq[CB_][KT], hv[KT], AB);
#define PAIR4(AA, AB, CA_, CB_, K0)                                            \
    PAIR_KT(AA, AB, CA_, CB_, K0 + 0) PAIR_KT(AA, AB, CA_, CB_, K0 + 1)        \
    PAIR_KT(AA, AB, CA_, CB_, K0 + 2) PAIR_KT(AA, AB, CA_, CB_, K0 + 3)
#define ST(C_, Q_) *reinterpret_cast<unsigned*>(hw_ + wrA[C_]) = Q_;

#define RSTEP(T_, CA, CB, CC, CD, P0, P1, P2, P3)                              \
    {                                                                          \
        P0 = *reinterpret_cast<const uint4*>(uptr);                            \
        P1 = *reinterpret_cast<const uint4*>(uptr + 8);                        \
        P2 = *reinterpret_cast<const uint4*>(uptr + 1024);                     \
        P3 = *reinterpret_cast<const uint4*>(uptr + 1032);                     \
        uptr += 32768;                                                         \
        const char* hb_ = h8 + ((T_) & 1) * 8192;                              \
        char* hw_ = h8 + (((T_) + 1) & 1) * 8192;                              \
        i32x4 hv[8];                                                           \
        _Pragma("unroll")                                                      \
        for (int kt = 0; kt < 8; ++kt)                                         \
            hv[kt] = *reinterpret_cast<const i32x4*>(                          \
                hb_ + rrow + ((kt * 64 + lq16) ^ swz));                        \
        const i32x4 ZR = {0, 0, 0, 0};                                         \
        i32x4 a0 = ZR, a1 = ZR, a2 = ZR, a3 = ZR;                              \
        i32x4 a4 = ZR, a5 = ZR, a6 = ZR, a7 = ZR;                              \
        PAIR4(a0, a1, 0, 1, 0) PAIR4(a0, a1, 0, 1, 4)                          \
        PAIR4(a2, a3, 2, 3, 0)                                                 \
        ST(0, tq4t(a0, sc2[0], CA.x, CA.y, ttab))                              \
        PAIR4(a2, a3, 2, 3, 4)                                                 \
        ST(1, tq4t(a1, sc2[1], CA.z, CA.w, ttab))                              \
        PAIR4(a4, a5, 4, 5, 0)                                                 \
        ST(2, tq4t(a2, sc2[2], CB.x, CB.y, ttab))                              \
        PAIR4(a4, a5, 4, 5, 4)                                                 \
        ST(3, tq4t(a3, sc2[3], CB.z, CB.w, ttab))                              \
        PAIR4(a6, a7, 6, 7, 0)                                                 \
        ST(4, tq4t(a4, sc2[4], CC.x, CC.y, ttab))                              \
        PAIR4(a6, a7, 6, 7, 4)                                                 \
        ST(5, tq4t(a5, sc2[5], CC.z, CC.w, ttab))                              \
        ST(6, tq4t(a6, sc2[6], CD.x, CD.y, ttab))                              \
        ST(7, tq4t(a7, sc2[7], CD.z, CD.w, ttab))                              \
        __syncthreads();                                                       \
    }

    #pragma unroll 1
    for (int t = 0; t < T_STEPS - 2; t += 2) {
        RSTEP(t, uXa, uXb, uXc, uXd, uYa, uYb, uYc, uYd)
        RSTEP(t + 1, uYa, uYb, uYc, uYd, uXa, uXb, uXc, uXd)
    }
    RSTEP(T_STEPS - 2, uXa, uXb, uXc, uXd, uYa, uYb, uYc, uYd)

    // ---- epilogue t = 2047: precise tanh, f32 store ----
    {
        const char* hb_ = h8 + ((T_STEPS - 1) & 1) * 8192;
        i32x4 hv[8];
        #pragma unroll
        for (int kt = 0; kt < 8; ++kt)
            hv[kt] = *reinterpret_cast<const i32x4*>(
                hb_ + rrow + ((kt * 64 + lq16) ^ swz));
        const i32x4 ZR = {0, 0, 0, 0};
        i32x4 a0 = ZR, a1 = ZR, a2 = ZR, a3 = ZR;
        i32x4 a4 = ZR, a5 = ZR, a6 = ZR, a7 = ZR;
        PAIR4(a0, a1, 0, 1, 0) PAIR4(a0, a1, 0, 1, 4)
        PAIR4(a2, a3, 2, 3, 0) PAIR4(a2, a3, 2, 3, 4)
        PAIR4(a4, a5, 4, 5, 0) PAIR4(a4, a5, 4, 5, 4)
        PAIR4(a6, a7, 6, 7, 0) PAIR4(a6, a7, 6, 7, 4)
        #pragma unroll
        for (int c = 0; c < 8; ++c) {
            const i32x4 a = (c == 0) ? a0 : (c == 1) ? a1 : (c == 2) ? a2 :
                            (c == 3) ? a3 : (c == 4) ? a4 : (c == 5) ? a5 :
                            (c == 6) ? a6 : a7;
            const uint4 uu = (c < 2) ? uYa : (c < 4) ? uYb : (c < 6) ? uYc : uYd;
            const unsigned w0 = (c & 1) ? uu.z : uu.x;
            const unsigned w1 = (c & 1) ? uu.w : uu.y;
            float th[4];
            #pragma unroll
            for (int r = 0; r < 4; ++r) {
                const unsigned word = (r < 2) ? w0 : w1;
                const float uf = __uint_as_float((r & 1) ? (word & 0xFFFF0000u) : (word << 16));
                const float x2 = fmaf((float)a[r], sc2[c][r], uf) * 0.0078125f;
                const float d = __builtin_amdgcn_exp2f(x2) + 1.f;
                th[r] = fmaf(__builtin_amdgcn_rcpf(d), -2.f, 1.f);
            }
            const float4 o = {th[0], th[1], th[2], th[3]};
            *reinterpret_cast<float4*>(out + (size_t)(g * 16 + lr) * HID +
                                       (8 * w + c) * 16 + 4 * lq) = o;
        }
    }
#undef RSTEP
#undef ST
#undef PAIR4
#undef PAIR_KT
#undef MFMA_I8
}

// ---------------------------------------------------------------------------
extern "C" void kernel_launch(void* const* d_in, const int* in_sizes, int n_in,
                              void* d_out, int out_size, void* d_ws, size_t ws_size,
                              hipStream_t stream) {
    const float* X   = (const float*)d_in[0];   // [2048][64][300]
    const float* Wih = (const float*)d_in[1];   // [512][300]
    const float* Whh = (const float*)d_in[2];   // [512][512]
    const float* bih = (const float*)d_in[3];   // [512]
    const float* bhh = (const float*)d_in[4];   // [512]
    float* out = (float*)d_out;                 // [64][512]
    unsigned short* U3 = (unsigned short*)d_ws; // 128 MB, rec-lane order

    u_gemm<<<dim3(2048 * 8), dim3(256), 0, stream>>>(X, Wih, bih, bhh, U3);
    rnn_rec<<<dim3(4), dim3(256), 0, stream>>>(Whh, U3, out);
}

// Round 12
// 2478.969 us; speedup vs baseline: 1.4880x; 1.4880x over previous
//
#include <hip/hip_runtime.h>
#include <hip/hip_bf16.h>

#define T_STEPS 2048
#define NB      64
#define IN_DIM  300
#define HID     512

typedef __attribute__((ext_vector_type(8))) short short8;   // 8 bf16 (4 VGPR)
typedef __attribute__((ext_vector_type(4))) float f32x4;    // MFMA f32 accum
typedef __attribute__((ext_vector_type(4))) int   i32x4;    // MFMA i8 frag/accum

#define USCALE 369.33000f                // 2*log2(e)*128 (table fixed-point)

static __device__ __forceinline__ unsigned short f2bf(float x) {
    unsigned int u = __float_as_uint(x);
    u = u + 0x7FFFu + ((u >> 16) & 1u);          // round-to-nearest-even
    return (unsigned short)(u >> 16);
}
static __device__ __forceinline__ unsigned cvtpk(float lo, float hi) {
    unsigned r;
    asm("v_cvt_pk_bf16_f32 %0, %1, %2" : "=v"(r) : "v"(lo), "v"(hi));
    return r;
}

// tanh+int8-quantize 4 values via LDS table. zero transcendentals.
static __device__ __forceinline__ unsigned tq4t(const i32x4 a, const f32x4 s,
                                                unsigned w0, unsigned w1,
                                                const unsigned char* tab) {
    unsigned q[4];
    #pragma unroll
    for (int r = 0; r < 4; ++r) {
        const unsigned word = (r < 2) ? w0 : w1;
        const float uf = __uint_as_float((r & 1) ? (word & 0xFFFF0000u) : (word << 16));
        const float xi = fmaf((float)a[r], s[r], uf) + 12582912.f;   // 2^23*1.5
        const float xc = __builtin_amdgcn_fmed3f(xi, 12580864.f, 12584959.f);
        q[r] = tab[__float_as_uint(xc) & 0xFFFu];                    // ds_read_u8
    }
    return __builtin_amdgcn_perm(
        __builtin_amdgcn_perm(q[3], q[2], 0x0C0C0400u),
        __builtin_amdgcn_perm(q[1], q[0], 0x0C0C0400u), 0x05040100u);
}

// ---------------------------------------------------------------------------
// Kernel 1: U = bf16( (x_t W_ih^T + b_ih + b_hh) * 2log2e*128 ), rec-lane
// order: U3[t][g(4)][wv(8)][lane(64)][c4(4)][r(4)]   (unchanged from R10)
// ---------------------------------------------------------------------------
__global__ __launch_bounds__(256, 4) void u_gemm(
    const float* __restrict__ X, const float* __restrict__ Wih,
    const float* __restrict__ bih, const float* __restrict__ bhh,
    unsigned short* __restrict__ U3)
{
    __shared__ unsigned short As[64 * 160];   // X rows (batch m)
    __shared__ unsigned short Bs[64 * 160];   // Wih rows (j)
    const int tid = threadIdx.x;
    const int m0 = (blockIdx.x >> 3) * 64, n0 = (blockIdx.x & 7) * 64;
    const int w = tid >> 6, l = tid & 63;
    const int lq = l >> 4, lr = l & 15;

    const f32x4 zv = {0.f, 0.f, 0.f, 0.f};
    f32x4 acc[2][2] = {{zv, zv}, {zv, zv}};   // [jt][mt]

    for (int kh = 0; kh < 2; ++kh) {
        const int kbase = kh * 160;
        __syncthreads();
        for (int i = tid; i < 64 * 40; i += 256) {
            const int r = i / 40, q = i - r * 40;
            const int kg = kbase + q * 4;
            unsigned int a0 = 0, a1 = 0, b0 = 0, b1 = 0;
            if (kg + 4 <= IN_DIM) {
                const float4 v = *reinterpret_cast<const float4*>(X + (size_t)(m0 + r) * IN_DIM + kg);
                a0 = (unsigned)f2bf(v.x) | ((unsigned)f2bf(v.y) << 16);
                a1 = (unsigned)f2bf(v.z) | ((unsigned)f2bf(v.w) << 16);
                const float4 u = *reinterpret_cast<const float4*>(Wih + (size_t)(n0 + r) * IN_DIM + kg);
                b0 = (unsigned)f2bf(u.x) | ((unsigned)f2bf(u.y) << 16);
                b1 = (unsigned)f2bf(u.z) | ((unsigned)f2bf(u.w) << 16);
            }
            int byte = r * 320 + q * 8; byte ^= ((r & 7) << 4);
            *reinterpret_cast<uint2*>(reinterpret_cast<char*>(As) + byte) = make_uint2(a0, a1);
            *reinterpret_cast<uint2*>(reinterpret_cast<char*>(Bs) + byte) = make_uint2(b0, b1);
        }
        __syncthreads();
        #pragma unroll
        for (int kc = 0; kc < 5; ++kc) {
            const int koff = kc * 64 + lq * 16;
            short8 xa[2], wb[2];
            #pragma unroll
            for (int mt = 0; mt < 2; ++mt) {
                const int row = (w >> 1) * 32 + mt * 16 + lr;       // X row (m)
                int abyte = row * 320 + koff; abyte ^= ((row & 7) << 4);
                xa[mt] = *reinterpret_cast<const short8*>(reinterpret_cast<const char*>(As) + abyte);
                const int jrow = (w & 1) * 32 + mt * 16 + lr;       // W row (j)
                int bbyte = jrow * 320 + koff; bbyte ^= ((jrow & 7) << 4);
                wb[mt] = *reinterpret_cast<const short8*>(reinterpret_cast<const char*>(Bs) + bbyte);
            }
            #pragma unroll
            for (int jt = 0; jt < 2; ++jt)
                #pragma unroll
                for (int mt = 0; mt < 2; ++mt)
                    acc[jt][mt] = __builtin_amdgcn_mfma_f32_16x16x32_bf16(
                        wb[jt], xa[mt], acc[jt][mt], 0, 0, 0);
        }
    }
    const int t = blockIdx.x >> 3;
    #pragma unroll
    for (int jt = 0; jt < 2; ++jt) {
        const int jb = n0 + (w & 1) * 32 + jt * 16 + 4 * lq;        // 4 consecutive j
        const float4 b1v = *reinterpret_cast<const float4*>(bih + jb);
        const float4 b2v = *reinterpret_cast<const float4*>(bhh + jb);
        const float4 bv = {(b1v.x + b2v.x) * USCALE, (b1v.y + b2v.y) * USCALE,
                           (b1v.z + b2v.z) * USCALE, (b1v.w + b2v.w) * USCALE};
        const int jtg = jb >> 4;
        const int wv2 = jtg >> 2, cc = jtg & 3;
        #pragma unroll
        for (int mt = 0; mt < 2; ++mt) {
            const int b = (w >> 1) * 32 + mt * 16 + lr;             // batch row
            const int g = b >> 4, lrr = b & 15;
            const f32x4 a = acc[jt][mt];
            uint2 p;
            p.x = cvtpk(fmaf(a[0], USCALE, bv.x), fmaf(a[1], USCALE, bv.y));
            p.y = cvtpk(fmaf(a[2], USCALE, bv.z), fmaf(a[3], USCALE, bv.w));
            const size_t sidx = ((((size_t)t * 4 + g) * 8 + wv2) * 64 + (lq * 16 + lrr)) * 16 + cc * 4;
            *reinterpret_cast<uint2*>(U3 + sidx) = p;
        }
    }
}

// ---------------------------------------------------------------------------
// Kernel 2: int8 recurrence (R10 skeleton: 4 blocks x 512 thr, 2 waves/SIMD,
// wq[4][8] register-stationary, table-tq, 1 barrier/step) + a FEASIBLE
// sched_group_barrier program: chains a0/a1 run first (16 MFMA, no VALU
// demanded — their tq consumers don't exist yet); then a2/a3's 16 MFMA are
// pinned 1:3-4 with tq(a0)/tq(a1) VALU + table ds_reads; tq(a2/a3) tail
// left unconstrained. This is the in-order-issue fix R7/R8 missed.
// ---------------------------------------------------------------------------
__global__ __launch_bounds__(512) __attribute__((amdgpu_waves_per_eu(2, 2)))
void rnn_rec(const float* __restrict__ Whh, const unsigned short* __restrict__ U3,
             float* __restrict__ out)
{
    const int g = blockIdx.x;                // 0..3
    const int tid = threadIdx.x;
    const int w = tid >> 6, l = tid & 63;
    const int lq = l >> 4, lr = l & 15;

    __shared__ char h8[2 * 16 * 512];        // [parity][m][k] swizzled
    __shared__ float wsc_lds[512];           // per-j scale (pre-scaled)
    __shared__ unsigned char ttab[4096];     // tanh+quant table (2's-compl idx)

    // ---- one-time: tanh table ----
    for (int i = tid; i < 4096; i += 512) {
        const int v = (i < 2048) ? i : i - 4096;
        const float x2 = (float)v * 0.0078125f;          // /128
        const float e = __builtin_amdgcn_exp2f(x2);
        const float th = (e - 1.f) / (e + 1.f);          // tanh(x2*ln2/2)
        ttab[i] = (unsigned char)(int)rintf(127.f * th);
    }

    // ---- one-time: quantize W to registers (static-indexed) ----
    i32x4 wq[4][8];
    #pragma unroll
    for (int c = 0; c < 4; ++c) {
        const float* wr = Whh + (size_t)((4 * w + c) * 16 + lr) * HID;
        float amax = 0.f;
        #pragma unroll
        for (int kt = 0; kt < 8; ++kt) {
            const int k0 = kt * 64 + lq * 16;
            #pragma unroll
            for (int q4 = 0; q4 < 4; ++q4) {
                const float4 v = *reinterpret_cast<const float4*>(wr + k0 + q4 * 4);
                amax = fmaxf(amax, fmaxf(fmaxf(fabsf(v.x), fabsf(v.y)),
                                         fmaxf(fabsf(v.z), fabsf(v.w))));
            }
        }
        amax = fmaxf(amax, __shfl_xor(amax, 16));
        amax = fmaxf(amax, __shfl_xor(amax, 32));    // full-row max
        const float inv = 127.f / amax;
        #pragma unroll
        for (int kt = 0; kt < 8; ++kt) {
            const int k0 = kt * 64 + lq * 16;
            i32x4 pk;
            #pragma unroll
            for (int q4 = 0; q4 < 4; ++q4) {
                const float4 v = *reinterpret_cast<const float4*>(wr + k0 + q4 * 4);
                const int q0 = (int)rintf(v.x * inv), q1 = (int)rintf(v.y * inv);
                const int q2 = (int)rintf(v.z * inv), q3 = (int)rintf(v.w * inv);
                pk[q4] = (q0 & 255) | ((q1 & 255) << 8) | ((q2 & 255) << 16) | (q3 << 24);
            }
            wq[c][kt] = pk;
        }
        if (lq == 0)
            wsc_lds[(4 * w + c) * 16 + lr] = amax * (USCALE / 16129.f);
    }
    // ---- h0 = 0 (both parities) ----
    for (int i = tid * 32; i < 2 * 16 * 512; i += 512 * 32) {
        *reinterpret_cast<uint4*>(h8 + i) = make_uint4(0, 0, 0, 0);
        *reinterpret_cast<uint4*>(h8 + i + 16) = make_uint4(0, 0, 0, 0);
    }
    __syncthreads();

    // per-lane D-column scales: j = (4w+c)*16 + 4lq + r
    f32x4 sc2[4];
    #pragma unroll
    for (int c = 0; c < 4; ++c) {
        const float4 s = *reinterpret_cast<const float4*>(&wsc_lds[(4 * w + c) * 16 + 4 * lq]);
        sc2[c] = f32x4{s.x, s.y, s.z, s.w};
    }

    const int swz = (lr & 7) << 4;
    const int rrow = lr * 512;
    const int lq16 = lq * 16;
    int wrA[4];
    #pragma unroll
    for (int c = 0; c < 4; ++c)
        wrA[c] = rrow + ((((4 * w + c) * 16) + 4 * lq) ^ swz);

    const unsigned short* ub = U3 + ((size_t)(g * 8 + w) * 64 + l) * 16;
    uint4 uA0 = *reinterpret_cast<const uint4*>(ub);
    uint4 uB0 = *reinterpret_cast<const uint4*>(ub + 8);
    const unsigned short* uptr = ub + 32768;
    uint4 uA1, uB1;

#define MFMA_I8(W_, H_, A_) __builtin_amdgcn_mfma_i32_16x16x64_i8(W_, H_, A_, 0, 0, 0)
#define SGB(M_, N_) __builtin_amdgcn_sched_group_barrier(M_, N_, 0)

#define RSTEP(T_, UA, UB, UAN, UBN)                                            \
    {                                                                          \
        UAN = *reinterpret_cast<const uint4*>(uptr);                           \
        UBN = *reinterpret_cast<const uint4*>(uptr + 8);                       \
        uptr += 32768;                                                         \
        const char* hb_ = h8 + ((T_) & 1) * 8192;                              \
        char* hw_ = h8 + (((T_) + 1) & 1) * 8192;                              \
        i32x4 hv[8];                                                           \
        _Pragma("unroll")                                                      \
        for (int kt = 0; kt < 8; ++kt)                                         \
            hv[kt] = *reinterpret_cast<const i32x4*>(                          \
                hb_ + rrow + ((kt * 64 + lq16) ^ swz));                        \
        i32x4 a0 = {0,0,0,0}, a1 = {0,0,0,0}, a2 = {0,0,0,0}, a3 = {0,0,0,0};  \
        _Pragma("unroll")                                                      \
        for (int kt = 0; kt < 8; ++kt) {                                       \
            a0 = MFMA_I8(wq[0][kt], hv[kt], a0);                               \
            a1 = MFMA_I8(wq[1][kt], hv[kt], a1);                               \
        }                                                                      \
        _Pragma("unroll")                                                      \
        for (int kt = 0; kt < 8; ++kt) {                                       \
            a2 = MFMA_I8(wq[2][kt], hv[kt], a2);                               \
            a3 = MFMA_I8(wq[3][kt], hv[kt], a3);                               \
        }                                                                      \
        *reinterpret_cast<unsigned*>(hw_ + wrA[0]) = tq4t(a0, sc2[0], UA.x, UA.y, ttab); \
        *reinterpret_cast<unsigned*>(hw_ + wrA[1]) = tq4t(a1, sc2[1], UA.z, UA.w, ttab); \
        *reinterpret_cast<unsigned*>(hw_ + wrA[2]) = tq4t(a2, sc2[2], UB.x, UB.y, ttab); \
        *reinterpret_cast<unsigned*>(hw_ + wrA[3]) = tq4t(a3, sc2[3], UB.z, UB.w, ttab); \
        /* schedule: U vmem, hv reads, a0/a1 (no VALU ready), then a2/a3     */\
        /* MFMAs 1:3-4 with tq(a0)/tq(a1) VALU + their 8 table ds_reads.     */\
        SGB(0x020, 2);                                                         \
        SGB(0x100, 8);                                                         \
        SGB(0x008, 16);                                                        \
        _Pragma("unroll")                                                      \
        for (int ii = 0; ii < 8; ++ii) {                                       \
            SGB(0x008, 1); SGB(0x002, 3); SGB(0x100, 1);                       \
            SGB(0x008, 1); SGB(0x002, 4);                                      \
        }                                                                      \
        SGB(0x200, 2);                                                         \
        __syncthreads();                                                       \
    }

    #pragma unroll 1
    for (int t = 0; t < T_STEPS - 2; t += 2) {
        RSTEP(t, uA0, uB0, uA1, uB1)
        RSTEP(t + 1, uA1, uB1, uA0, uB0)
    }
    RSTEP(T_STEPS - 2, uA0, uB0, uA1, uB1)

    // ---- epilogue t = 2047: precise tanh, f32 store ----
    {
        const char* hb_ = h8 + ((T_STEPS - 1) & 1) * 8192;
        i32x4 a[4] = {{0,0,0,0}, {0,0,0,0}, {0,0,0,0}, {0,0,0,0}};
        #pragma unroll
        for (int kt = 0; kt < 8; ++kt) {
            const i32x4 hv = *reinterpret_cast<const i32x4*>(
                hb_ + rrow + ((kt * 64 + lq16) ^ swz));
            a[0] = MFMA_I8(wq[0][kt], hv, a[0]);
            a[1] = MFMA_I8(wq[1][kt], hv, a[1]);
            a[2] = MFMA_I8(wq[2][kt], hv, a[2]);
            a[3] = MFMA_I8(wq[3][kt], hv, a[3]);
        }
        #pragma unroll
        for (int c = 0; c < 4; ++c) {
            const unsigned w0 = (c == 0) ? uA1.x : (c == 1) ? uA1.z : (c == 2) ? uB1.x : uB1.z;
            const unsigned w1 = (c == 0) ? uA1.y : (c == 1) ? uA1.w : (c == 2) ? uB1.y : uB1.w;
            float th[4];
            #pragma unroll
            for (int r = 0; r < 4; ++r) {
                const unsigned word = (r < 2) ? w0 : w1;
                const float uf = __uint_as_float((r & 1) ? (word & 0xFFFF0000u) : (word << 16));
                const float x2 = fmaf((float)a[c][r], sc2[c][r], uf) * 0.0078125f;
                const float d = __builtin_amdgcn_exp2f(x2) + 1.f;
                th[r] = fmaf(__builtin_amdgcn_rcpf(d), -2.f, 1.f);
            }
            const float4 o = {th[0], th[1], th[2], th[3]};
            *reinterpret_cast<float4*>(out + (size_t)(g * 16 + lr) * HID +
                                       (4 * w + c) * 16 + 4 * lq) = o;
        }
    }
#undef RSTEP
#undef SGB
#undef MFMA_I8
}

// ---------------------------------------------------------------------------
extern "C" void kernel_launch(void* const* d_in, const int* in_sizes, int n_in,
                              void* d_out, int out_size, void* d_ws, size_t ws_size,
                              hipStream_t stream) {
    const float* X   = (const float*)d_in[0];   // [2048][64][300]
    const float* Wih = (const float*)d_in[1];   // [512][300]
    const float* Whh = (const float*)d_in[2];   // [512][512]
    const float* bih = (const float*)d_in[3];   // [512]
    const float* bhh = (const float*)d_in[4];   // [512]
    float* out = (float*)d_out;                 // [64][512]
    unsigned short* U3 = (unsigned short*)d_ws; // 128 MB, rec-lane order

    u_gemm<<<dim3(2048 * 8), dim3(256), 0, stream>>>(X, Wih, bih, bhh, U3);
    rnn_rec<<<dim3(4), dim3(512), 0, stream>>>(Whh, U3, out);
}

// Round 13
// 2289.607 us; speedup vs baseline: 1.6110x; 1.0827x over previous
//
#include <hip/hip_runtime.h>
#include <hip/hip_bf16.h>

#define T_STEPS 2048
#define NB      64
#define IN_DIM  300
#define HID     512

typedef __attribute__((ext_vector_type(8))) short short8;   // 8 bf16 (4 VGPR)
typedef __attribute__((ext_vector_type(4))) float f32x4;    // MFMA f32 accum
typedef __attribute__((ext_vector_type(4))) int   i32x4;    // MFMA i8 frag/accum

#define USCALE 369.33000f                // 2*log2(e)*128 (table fixed-point)

static __device__ __forceinline__ unsigned short f2bf(float x) {
    unsigned int u = __float_as_uint(x);
    u = u + 0x7FFFu + ((u >> 16) & 1u);          // round-to-nearest-even
    return (unsigned short)(u >> 16);
}
static __device__ __forceinline__ unsigned cvtpk(float lo, float hi) {
    unsigned r;
    asm("v_cvt_pk_bf16_f32 %0, %1, %2" : "=v"(r) : "v"(lo), "v"(hi));
    return r;
}

// tanh+int8-quantize 4 values via LDS table. zero transcendentals.
static __device__ __forceinline__ unsigned tq4t(const i32x4 a, const f32x4 s,
                                                unsigned w0, unsigned w1,
                                                const unsigned char* tab) {
    unsigned q[4];
    #pragma unroll
    for (int r = 0; r < 4; ++r) {
        const unsigned word = (r < 2) ? w0 : w1;
        const float uf = __uint_as_float((r & 1) ? (word & 0xFFFF0000u) : (word << 16));
        const float xi = fmaf((float)a[r], s[r], uf) + 12582912.f;   // 2^23*1.5
        const float xc = __builtin_amdgcn_fmed3f(xi, 12580864.f, 12584959.f);
        q[r] = tab[__float_as_uint(xc) & 0xFFFu];                    // ds_read_u8
    }
    return __builtin_amdgcn_perm(
        __builtin_amdgcn_perm(q[3], q[2], 0x0C0C0400u),
        __builtin_amdgcn_perm(q[1], q[0], 0x0C0C0400u), 0x05040100u);
}

// ---------------------------------------------------------------------------
// Kernel 1: U = bf16( (x_t W_ih^T + b_ih + b_hh) * 2log2e*128 ), m-split
// rec-lane order: U3[t][bb(8)][wv(8)][lane(64)][8]
//   value(j,b): bb=b>>3, m=b&7, wv=(j>>6), c=(j>>4)&3,
//   lane = ((j>>2)&3)*16 + (c&2 ? 8:0) + m, shorts (c&1)*4 + {r packed}
// ---------------------------------------------------------------------------
__global__ __launch_bounds__(256, 4) void u_gemm(
    const float* __restrict__ X, const float* __restrict__ Wih,
    const float* __restrict__ bih, const float* __restrict__ bhh,
    unsigned short* __restrict__ U3)
{
    __shared__ unsigned short As[64 * 160];   // X rows (batch m)
    __shared__ unsigned short Bs[64 * 160];   // Wih rows (j)
    const int tid = threadIdx.x;
    const int m0 = (blockIdx.x >> 3) * 64, n0 = (blockIdx.x & 7) * 64;
    const int w = tid >> 6, l = tid & 63;
    const int lq = l >> 4, lr = l & 15;

    const f32x4 zv = {0.f, 0.f, 0.f, 0.f};
    f32x4 acc[2][2] = {{zv, zv}, {zv, zv}};   // [jt][mt]

    for (int kh = 0; kh < 2; ++kh) {
        const int kbase = kh * 160;
        __syncthreads();
        for (int i = tid; i < 64 * 40; i += 256) {
            const int r = i / 40, q = i - r * 40;
            const int kg = kbase + q * 4;
            unsigned int a0 = 0, a1 = 0, b0 = 0, b1 = 0;
            if (kg + 4 <= IN_DIM) {
                const float4 v = *reinterpret_cast<const float4*>(X + (size_t)(m0 + r) * IN_DIM + kg);
                a0 = (unsigned)f2bf(v.x) | ((unsigned)f2bf(v.y) << 16);
                a1 = (unsigned)f2bf(v.z) | ((unsigned)f2bf(v.w) << 16);
                const float4 u = *reinterpret_cast<const float4*>(Wih + (size_t)(n0 + r) * IN_DIM + kg);
                b0 = (unsigned)f2bf(u.x) | ((unsigned)f2bf(u.y) << 16);
                b1 = (unsigned)f2bf(u.z) | ((unsigned)f2bf(u.w) << 16);
            }
            int byte = r * 320 + q * 8; byte ^= ((r & 7) << 4);
            *reinterpret_cast<uint2*>(reinterpret_cast<char*>(As) + byte) = make_uint2(a0, a1);
            *reinterpret_cast<uint2*>(reinterpret_cast<char*>(Bs) + byte) = make_uint2(b0, b1);
        }
        __syncthreads();
        #pragma unroll
        for (int kc = 0; kc < 5; ++kc) {
            const int koff = kc * 64 + lq * 16;
            short8 xa[2], wb[2];
            #pragma unroll
            for (int mt = 0; mt < 2; ++mt) {
                const int row = (w >> 1) * 32 + mt * 16 + lr;       // X row (m)
                int abyte = row * 320 + koff; abyte ^= ((row & 7) << 4);
                xa[mt] = *reinterpret_cast<const short8*>(reinterpret_cast<const char*>(As) + abyte);
                const int jrow = (w & 1) * 32 + mt * 16 + lr;       // W row (j)
                int bbyte = jrow * 320 + koff; bbyte ^= ((jrow & 7) << 4);
                wb[mt] = *reinterpret_cast<const short8*>(reinterpret_cast<const char*>(Bs) + bbyte);
            }
            #pragma unroll
            for (int jt = 0; jt < 2; ++jt)
                #pragma unroll
                for (int mt = 0; mt < 2; ++mt)
                    acc[jt][mt] = __builtin_amdgcn_mfma_f32_16x16x32_bf16(
                        wb[jt], xa[mt], acc[jt][mt], 0, 0, 0);
        }
    }
    const int t = blockIdx.x >> 3;
    #pragma unroll
    for (int jt = 0; jt < 2; ++jt) {
        const int jb = n0 + (w & 1) * 32 + jt * 16 + 4 * lq;        // 4 consecutive j
        const float4 b1v = *reinterpret_cast<const float4*>(bih + jb);
        const float4 b2v = *reinterpret_cast<const float4*>(bhh + jb);
        const float4 bv = {(b1v.x + b2v.x) * USCALE, (b1v.y + b2v.y) * USCALE,
                           (b1v.z + b2v.z) * USCALE, (b1v.w + b2v.w) * USCALE};
        const int jtile = jb >> 4;
        const int wvv = jtile >> 2, cc = jtile & 3;
        #pragma unroll
        for (int mt = 0; mt < 2; ++mt) {
            const int b = (w >> 1) * 32 + mt * 16 + lr;             // batch 0..63
            const int bb = b >> 3, m = b & 7;
            const int lane = ((jb >> 2) & 3) * 16 + ((cc & 2) ? 8 : 0) + m;
            const f32x4 a = acc[jt][mt];
            uint2 p;
            p.x = cvtpk(fmaf(a[0], USCALE, bv.x), fmaf(a[1], USCALE, bv.y));
            p.y = cvtpk(fmaf(a[2], USCALE, bv.z), fmaf(a[3], USCALE, bv.w));
            const size_t sidx = ((((size_t)t * 8 + bb) * 8 + wvv) * 64 + lane) * 8 + (cc & 1) * 4;
            *reinterpret_cast<uint2*>(U3 + sidx) = p;
        }
    }
}

// ---------------------------------------------------------------------------
// Kernel 2: int8 recurrence, M-SPLIT across 8 CUs (zero communication).
// Block bb owns batches bb*8..bb*8+7, full 512 cols. Same 256 MFMA/block/step
// (M-dim half-padded -> matrix time unchanged) but tanh/gather/h-LDS HALVED.
// After MFMA, __shfl_xor(8) moves chains a2/a3 to idle lanes lr>=8 so all 64
// lanes run 2 tq4t (branchless). h rows rotated by m*64 (conflict-free reads);
// MFMA B cols 8..15 read a broadcast zero stripe. 1 barrier/step.
// ---------------------------------------------------------------------------
__global__ __launch_bounds__(512) __attribute__((amdgpu_waves_per_eu(2, 2)))
void rnn_rec(const float* __restrict__ Whh, const unsigned short* __restrict__ U3,
             float* __restrict__ out)
{
    const int bb = blockIdx.x;               // 0..7
    const int tid = threadIdx.x;
    const int w = tid >> 6, l = tid & 63;
    const int lq = l >> 4, lr = l & 15;

    __shared__ char h8[2 * 4096 + 16];       // [parity][m 8][k 512 rotated] + zero stripe
    __shared__ float wsc_lds[512];           // per-j scale (pre-scaled)
    __shared__ unsigned char ttab[4096];     // tanh+quant table (2's-compl idx)

    // ---- one-time: tanh table ----
    for (int i = tid; i < 4096; i += 512) {
        const int v = (i < 2048) ? i : i - 4096;
        const float x2 = (float)v * 0.0078125f;          // /128
        const float e = __builtin_amdgcn_exp2f(x2);
        const float th = (e - 1.f) / (e + 1.f);          // tanh(x2*ln2/2)
        ttab[i] = (unsigned char)(int)rintf(127.f * th);
    }

    // ---- one-time: quantize W to registers (wave owns j-tiles 4w..4w+3) ----
    i32x4 wq[4][8];
    #pragma unroll
    for (int c = 0; c < 4; ++c) {
        const float* wr = Whh + (size_t)((4 * w + c) * 16 + lr) * HID;
        float amax = 0.f;
        #pragma unroll
        for (int kt = 0; kt < 8; ++kt) {
            const int k0 = kt * 64 + lq * 16;
            #pragma unroll
            for (int q4 = 0; q4 < 4; ++q4) {
                const float4 v = *reinterpret_cast<const float4*>(wr + k0 + q4 * 4);
                amax = fmaxf(amax, fmaxf(fmaxf(fabsf(v.x), fabsf(v.y)),
                                         fmaxf(fabsf(v.z), fabsf(v.w))));
            }
        }
        amax = fmaxf(amax, __shfl_xor(amax, 16));
        amax = fmaxf(amax, __shfl_xor(amax, 32));    // full-row max
        const float inv = 127.f / amax;
        #pragma unroll
        for (int kt = 0; kt < 8; ++kt) {
            const int k0 = kt * 64 + lq * 16;
            i32x4 pk;
            #pragma unroll
            for (int q4 = 0; q4 < 4; ++q4) {
                const float4 v = *reinterpret_cast<const float4*>(wr + k0 + q4 * 4);
                const int q0 = (int)rintf(v.x * inv), q1 = (int)rintf(v.y * inv);
                const int q2 = (int)rintf(v.z * inv), q3 = (int)rintf(v.w * inv);
                pk[q4] = (q0 & 255) | ((q1 & 255) << 8) | ((q2 & 255) << 16) | (q3 << 24);
            }
            wq[c][kt] = pk;
        }
        if (lq == 0)
            wsc_lds[(4 * w + c) * 16 + lr] = amax * (USCALE / 16129.f);
    }
    // ---- h0 = 0 (both parities + zero stripe) ----
    for (int i = tid; i < 2052; i += 512)
        reinterpret_cast<unsigned*>(h8)[i] = 0;
    __syncthreads();

    // ---- per-lane roles ----
    const bool hi = (lr >= 8);
    const int c0 = hi ? 2 : 0;
    const int m = lr & 7;

    // scales for this lane's two c-chunks
    f32x4 scA, scB;
    {
        const float4 s0 = *reinterpret_cast<const float4*>(&wsc_lds[(4 * w + c0) * 16 + 4 * lq]);
        const float4 s1 = *reinterpret_cast<const float4*>(&wsc_lds[(4 * w + c0 + 1) * 16 + 4 * lq]);
        scA = f32x4{s0.x, s0.y, s0.z, s0.w};
        scB = f32x4{s1.x, s1.y, s1.z, s1.w};
    }

    // hv read addrs (t-invariant): lo lanes scatter, hi lanes broadcast zero stripe
    int hvP0[8], hvP1[8];
    #pragma unroll
    for (int kt = 0; kt < 8; ++kt) {
        const int a = lr * 512 + ((kt * 64 + lq * 16 + lr * 64) & 511);
        hvP0[kt] = hi ? 8192 : a;
        hvP1[kt] = hi ? 8192 : a + 4096;
    }
    // h write addrs: all lanes write batch m, their 2 j-chunks
    const int j00 = (4 * w + c0) * 16 + 4 * lq;
    const int j01 = j00 + 16;
    const int w0p0 = m * 512 + ((j00 + m * 64) & 511);
    const int w1p0 = m * 512 + ((j01 + m * 64) & 511);
    const int w0p1 = w0p0 + 4096, w1p1 = w1p0 + 4096;

    const unsigned short* uptr = U3 + ((size_t)(bb * 8 + w) * 64 + l) * 8;
    uint4 uX = *reinterpret_cast<const uint4*>(uptr);
    uptr += 32768;
    uint4 uY;

#define MFMA_I8(W_, H_, A_) __builtin_amdgcn_mfma_i32_16x16x64_i8(W_, H_, A_, 0, 0, 0)

#define RSTEP(P, UC, UN)                                                       \
    {                                                                          \
        UN = *reinterpret_cast<const uint4*>(uptr);                            \
        uptr += 32768;                                                         \
        i32x4 hv[8];                                                           \
        _Pragma("unroll")                                                      \
        for (int kt = 0; kt < 8; ++kt)                                         \
            hv[kt] = *reinterpret_cast<const i32x4*>(h8 + ((P) ? hvP1[kt] : hvP0[kt])); \
        i32x4 a0 = {0,0,0,0}, a1 = {0,0,0,0}, a2 = {0,0,0,0}, a3 = {0,0,0,0};  \
        _Pragma("unroll")                                                      \
        for (int kt = 0; kt < 8; ++kt) {                                       \
            a0 = MFMA_I8(wq[0][kt], hv[kt], a0);                               \
            a1 = MFMA_I8(wq[1][kt], hv[kt], a1);                               \
        }                                                                      \
        _Pragma("unroll")                                                      \
        for (int kt = 0; kt < 8; ++kt) {                                       \
            a2 = MFMA_I8(wq[2][kt], hv[kt], a2);                               \
            a3 = MFMA_I8(wq[3][kt], hv[kt], a3);                               \
        }                                                                      \
        i32x4 b0, b1;                                                          \
        _Pragma("unroll")                                                      \
        for (int r = 0; r < 4; ++r) {                                          \
            const int x2r = __shfl_xor(a2[r], 8);                              \
            const int x3r = __shfl_xor(a3[r], 8);                              \
            b0[r] = hi ? x2r : a0[r];                                          \
            b1[r] = hi ? x3r : a1[r];                                          \
        }                                                                      \
        const unsigned q0 = tq4t(b0, scA, UC.x, UC.y, ttab);                   \
        const unsigned q1 = tq4t(b1, scB, UC.z, UC.w, ttab);                   \
        *reinterpret_cast<unsigned*>(h8 + ((P) ? w0p0 : w0p1)) = q0;           \
        *reinterpret_cast<unsigned*>(h8 + ((P) ? w1p0 : w1p1)) = q1;           \
        __syncthreads();                                                       \
    }

    #pragma unroll 1
    for (int it = 0; it < 1023; ++it) {
        RSTEP(0, uX, uY)     // even t: read par0, write par1
        RSTEP(1, uY, uX)     // odd t
    }
    RSTEP(0, uX, uY)         // t = 2046, prefetches t = 2047 into uY

    // ---- epilogue t = 2047 (read parity 1): precise tanh, f32 store ----
    {
        i32x4 hv[8];
        #pragma unroll
        for (int kt = 0; kt < 8; ++kt)
            hv[kt] = *reinterpret_cast<const i32x4*>(h8 + hvP1[kt]);
        i32x4 a0 = {0,0,0,0}, a1 = {0,0,0,0}, a2 = {0,0,0,0}, a3 = {0,0,0,0};
        #pragma unroll
        for (int kt = 0; kt < 8; ++kt) {
            a0 = MFMA_I8(wq[0][kt], hv[kt], a0);
            a1 = MFMA_I8(wq[1][kt], hv[kt], a1);
            a2 = MFMA_I8(wq[2][kt], hv[kt], a2);
            a3 = MFMA_I8(wq[3][kt], hv[kt], a3);
        }
        i32x4 b0, b1;
        #pragma unroll
        for (int r = 0; r < 4; ++r) {
            const int x2r = __shfl_xor(a2[r], 8);
            const int x3r = __shfl_xor(a3[r], 8);
            b0[r] = hi ? x2r : a0[r];
            b1[r] = hi ? x3r : a1[r];
        }
        float th0[4], th1[4];
        #pragma unroll
        for (int r = 0; r < 4; ++r) {
            const unsigned wd0 = (r < 2) ? uY.x : uY.y;
            const unsigned wd1 = (r < 2) ? uY.z : uY.w;
            const float uf0 = __uint_as_float((r & 1) ? (wd0 & 0xFFFF0000u) : (wd0 << 16));
            const float uf1 = __uint_as_float((r & 1) ? (wd1 & 0xFFFF0000u) : (wd1 << 16));
            const float xa = fmaf((float)b0[r], scA[r], uf0) * 0.0078125f;
            const float xb = fmaf((float)b1[r], scB[r], uf1) * 0.0078125f;
            const float da = __builtin_amdgcn_exp2f(xa) + 1.f;
            const float db = __builtin_amdgcn_exp2f(xb) + 1.f;
            th0[r] = fmaf(__builtin_amdgcn_rcpf(da), -2.f, 1.f);
            th1[r] = fmaf(__builtin_amdgcn_rcpf(db), -2.f, 1.f);
        }
        float* orow = out + (size_t)(bb * 8 + m) * HID;
        *reinterpret_cast<float4*>(orow + j00) = float4{th0[0], th0[1], th0[2], th0[3]};
        *reinterpret_cast<float4*>(orow + j01) = float4{th1[0], th1[1], th1[2], th1[3]};
    }
#undef RSTEP
#undef MFMA_I8
}

// ---------------------------------------------------------------------------
extern "C" void kernel_launch(void* const* d_in, const int* in_sizes, int n_in,
                              void* d_out, int out_size, void* d_ws, size_t ws_size,
                              hipStream_t stream) {
    const float* X   = (const float*)d_in[0];   // [2048][64][300]
    const float* Wih = (const float*)d_in[1];   // [512][300]
    const float* Whh = (const float*)d_in[2];   // [512][512]
    const float* bih = (const float*)d_in[3];   // [512]
    const float* bhh = (const float*)d_in[4];   // [512]
    float* out = (float*)d_out;                 // [64][512]
    unsigned short* U3 = (unsigned short*)d_ws; // 128 MB, m-split rec-lane order

    u_gemm<<<dim3(2048 * 8), dim3(256), 0, stream>>>(X, Wih, bih, bhh, U3);
    rnn_rec<<<dim3(8), dim3(512), 0, stream>>>(Whh, U3, out);
}

// Round 14
// 2147.377 us; speedup vs baseline: 1.7177x; 1.0662x over previous
//
#include <hip/hip_runtime.h>
#include <hip/hip_bf16.h>

#define T_STEPS 2048
#define NB      64
#define IN_DIM  300
#define HID     512

typedef __attribute__((ext_vector_type(8))) short short8;   // 8 bf16 (4 VGPR)
typedef __attribute__((ext_vector_type(4))) float f32x4;    // MFMA f32 accum
typedef __attribute__((ext_vector_type(4))) int   i32x4;    // MFMA i8 frag/accum

#define S2L 2.8853900817779268f          // 2*log2(e): exp(2x) = 2^(x*S2L)

static __device__ __forceinline__ unsigned short f2bf(float x) {
    unsigned int u = __float_as_uint(x);
    u = u + 0x7FFFu + ((u >> 16) & 1u);          // round-to-nearest-even
    return (unsigned short)(u >> 16);
}
static __device__ __forceinline__ unsigned cvtpk(float lo, float hi) {
    unsigned r;
    asm("v_cvt_pk_bf16_f32 %0, %1, %2" : "=v"(r) : "v"(lo), "v"(hi));
    return r;
}

// tanh+int8-quantize 4 values: x2 = cvt(acc)*sc + u2 (pre-scaled by 2log2e).
// th = 1-2/(2^x2+1); rcp via bit-seed + 1 Newton (R8-verified, absmax 0.0100);
// q = RNE(127*th) via add-magic; pack via v_perm. No LDS gathers.
static __device__ __forceinline__ unsigned tq4nr(const i32x4 a, const f32x4 s,
                                                 unsigned w0, unsigned w1) {
    unsigned q[4];
    #pragma unroll
    for (int r = 0; r < 4; ++r) {
        const unsigned word = (r < 2) ? w0 : w1;
        const float uf = __uint_as_float((r & 1) ? (word & 0xFFFF0000u) : (word << 16));
        const float x2 = fmaf((float)a[r], s[r], uf);
        const float d = __builtin_amdgcn_exp2f(x2) + 1.f;
        const float r0 = __uint_as_float(0x7EF311C3u - __float_as_uint(d));
        const float rr = r0 * (2.f - d * r0);            // 1 Newton step
        q[r] = __float_as_uint(fmaf(rr, -254.f, 12583039.f));  // byte0 = int8
    }
    return __builtin_amdgcn_perm(
        __builtin_amdgcn_perm(q[3], q[2], 0x0C0C0400u),
        __builtin_amdgcn_perm(q[1], q[0], 0x0C0C0400u), 0x05040100u);
}

// ---------------------------------------------------------------------------
// Kernel 1: U = bf16( (x_t W_ih^T + b_ih + b_hh) * 2log2e ), m-split rec-lane
// order (unchanged from R13). Block mapping is XCD-AWARE: the 8 n-blocks
// sharing one X m-tile land on the SAME XCD within a 56-block window, so the
// X tile is fetched from HBM once and L2-hit 7 times (was 8x HBM overfetch).
// ---------------------------------------------------------------------------
__global__ __launch_bounds__(256, 4) void u_gemm(
    const float* __restrict__ X, const float* __restrict__ Wih,
    const float* __restrict__ bih, const float* __restrict__ bhh,
    unsigned short* __restrict__ U3)
{
    __shared__ unsigned short As[64 * 160];   // X rows (batch m)
    __shared__ unsigned short Bs[64 * 160];   // Wih rows (j)
    const int tid = threadIdx.x;
    const int bxx = blockIdx.x;
    const int xcd_c = bxx & 7, k8 = (bxx >> 3) & 7;
    const int mi = (bxx >> 6) * 8 + xcd_c;    // m-tile (= timestep t), 0..2047
    const int m0 = mi * 64, n0 = k8 * 64;
    const int w = tid >> 6, l = tid & 63;
    const int lq = l >> 4, lr = l & 15;

    const f32x4 zv = {0.f, 0.f, 0.f, 0.f};
    f32x4 acc[2][2] = {{zv, zv}, {zv, zv}};   // [jt][mt]

    for (int kh = 0; kh < 2; ++kh) {
        const int kbase = kh * 160;
        __syncthreads();
        for (int i = tid; i < 64 * 40; i += 256) {
            const int r = i / 40, q = i - r * 40;
            const int kg = kbase + q * 4;
            unsigned int a0 = 0, a1 = 0, b0 = 0, b1 = 0;
            if (kg + 4 <= IN_DIM) {
                const float4 v = *reinterpret_cast<const float4*>(X + (size_t)(m0 + r) * IN_DIM + kg);
                a0 = (unsigned)f2bf(v.x) | ((unsigned)f2bf(v.y) << 16);
                a1 = (unsigned)f2bf(v.z) | ((unsigned)f2bf(v.w) << 16);
                const float4 u = *reinterpret_cast<const float4*>(Wih + (size_t)(n0 + r) * IN_DIM + kg);
                b0 = (unsigned)f2bf(u.x) | ((unsigned)f2bf(u.y) << 16);
                b1 = (unsigned)f2bf(u.z) | ((unsigned)f2bf(u.w) << 16);
            }
            int byte = r * 320 + q * 8; byte ^= ((r & 7) << 4);
            *reinterpret_cast<uint2*>(reinterpret_cast<char*>(As) + byte) = make_uint2(a0, a1);
            *reinterpret_cast<uint2*>(reinterpret_cast<char*>(Bs) + byte) = make_uint2(b0, b1);
        }
        __syncthreads();
        #pragma unroll
        for (int kc = 0; kc < 5; ++kc) {
            const int koff = kc * 64 + lq * 16;
            short8 xa[2], wb[2];
            #pragma unroll
            for (int mt = 0; mt < 2; ++mt) {
                const int row = (w >> 1) * 32 + mt * 16 + lr;       // X row (m)
                int abyte = row * 320 + koff; abyte ^= ((row & 7) << 4);
                xa[mt] = *reinterpret_cast<const short8*>(reinterpret_cast<const char*>(As) + abyte);
                const int jrow = (w & 1) * 32 + mt * 16 + lr;       // W row (j)
                int bbyte = jrow * 320 + koff; bbyte ^= ((jrow & 7) << 4);
                wb[mt] = *reinterpret_cast<const short8*>(reinterpret_cast<const char*>(Bs) + bbyte);
            }
            #pragma unroll
            for (int jt = 0; jt < 2; ++jt)
                #pragma unroll
                for (int mt = 0; mt < 2; ++mt)
                    acc[jt][mt] = __builtin_amdgcn_mfma_f32_16x16x32_bf16(
                        wb[jt], xa[mt], acc[jt][mt], 0, 0, 0);
        }
    }
    const int t = mi;
    #pragma unroll
    for (int jt = 0; jt < 2; ++jt) {
        const int jb = n0 + (w & 1) * 32 + jt * 16 + 4 * lq;        // 4 consecutive j
        const float4 b1v = *reinterpret_cast<const float4*>(bih + jb);
        const float4 b2v = *reinterpret_cast<const float4*>(bhh + jb);
        const float4 bv = {(b1v.x + b2v.x) * S2L, (b1v.y + b2v.y) * S2L,
                           (b1v.z + b2v.z) * S2L, (b1v.w + b2v.w) * S2L};
        const int jtile = jb >> 4;
        const int wvv = jtile >> 2, cc = jtile & 3;
        #pragma unroll
        for (int mt = 0; mt < 2; ++mt) {
            const int b = (w >> 1) * 32 + mt * 16 + lr;             // batch 0..63
            const int bb = b >> 3, m = b & 7;
            const int lane = ((jb >> 2) & 3) * 16 + ((cc & 2) ? 8 : 0) + m;
            const f32x4 a = acc[jt][mt];
            uint2 p;
            p.x = cvtpk(fmaf(a[0], S2L, bv.x), fmaf(a[1], S2L, bv.y));
            p.y = cvtpk(fmaf(a[2], S2L, bv.z), fmaf(a[3], S2L, bv.w));
            const size_t sidx = ((((size_t)t * 8 + bb) * 8 + wvv) * 64 + lane) * 8 + (cc & 1) * 4;
            *reinterpret_cast<uint2*>(U3 + sidx) = p;
        }
    }
}

// ---------------------------------------------------------------------------
// Kernel 2: int8 recurrence, M-SPLIT across 8 CUs (R13 skeleton) with
// TRANS-based tanh+quant (exp2 + NR-rcp, tq4nr) instead of the LDS table:
// at 8 values/lane the trans path (16 trans-instr/wave) beats the table's
// ~475 conflict-cy/CU/step of random ds_read_u8 gathers, and unloads the
// LDS pipe serving hv reads + h writes. Everything else unchanged.
// ---------------------------------------------------------------------------
__global__ __launch_bounds__(512) __attribute__((amdgpu_waves_per_eu(2, 2)))
void rnn_rec(const float* __restrict__ Whh, const unsigned short* __restrict__ U3,
             float* __restrict__ out)
{
    const int bb = blockIdx.x;               // 0..7
    const int tid = threadIdx.x;
    const int w = tid >> 6, l = tid & 63;
    const int lq = l >> 4, lr = l & 15;

    __shared__ char h8[2 * 4096 + 16];       // [parity][m 8][k 512 rotated] + zero stripe
    __shared__ float wsc_lds[512];           // per-j scale (pre-scaled by 2log2e)

    // ---- one-time: quantize W to registers (wave owns j-tiles 4w..4w+3) ----
    i32x4 wq[4][8];
    #pragma unroll
    for (int c = 0; c < 4; ++c) {
        const float* wr = Whh + (size_t)((4 * w + c) * 16 + lr) * HID;
        float amax = 0.f;
        #pragma unroll
        for (int kt = 0; kt < 8; ++kt) {
            const int k0 = kt * 64 + lq * 16;
            #pragma unroll
            for (int q4 = 0; q4 < 4; ++q4) {
                const float4 v = *reinterpret_cast<const float4*>(wr + k0 + q4 * 4);
                amax = fmaxf(amax, fmaxf(fmaxf(fabsf(v.x), fabsf(v.y)),
                                         fmaxf(fabsf(v.z), fabsf(v.w))));
            }
        }
        amax = fmaxf(amax, __shfl_xor(amax, 16));
        amax = fmaxf(amax, __shfl_xor(amax, 32));    // full-row max
        const float inv = 127.f / amax;
        #pragma unroll
        for (int kt = 0; kt < 8; ++kt) {
            const int k0 = kt * 64 + lq * 16;
            i32x4 pk;
            #pragma unroll
            for (int q4 = 0; q4 < 4; ++q4) {
                const float4 v = *reinterpret_cast<const float4*>(wr + k0 + q4 * 4);
                const int q0 = (int)rintf(v.x * inv), q1 = (int)rintf(v.y * inv);
                const int q2 = (int)rintf(v.z * inv), q3 = (int)rintf(v.w * inv);
                pk[q4] = (q0 & 255) | ((q1 & 255) << 8) | ((q2 & 255) << 16) | (q3 << 24);
            }
            wq[c][kt] = pk;
        }
        if (lq == 0)
            wsc_lds[(4 * w + c) * 16 + lr] = amax * (S2L / 16129.f);
    }
    // ---- h0 = 0 (both parities + zero stripe) ----
    for (int i = tid; i < 2052; i += 512)
        reinterpret_cast<unsigned*>(h8)[i] = 0;
    __syncthreads();

    // ---- per-lane roles ----
    const bool hi = (lr >= 8);
    const int c0 = hi ? 2 : 0;
    const int m = lr & 7;

    // scales for this lane's two c-chunks
    f32x4 scA, scB;
    {
        const float4 s0 = *reinterpret_cast<const float4*>(&wsc_lds[(4 * w + c0) * 16 + 4 * lq]);
        const float4 s1 = *reinterpret_cast<const float4*>(&wsc_lds[(4 * w + c0 + 1) * 16 + 4 * lq]);
        scA = f32x4{s0.x, s0.y, s0.z, s0.w};
        scB = f32x4{s1.x, s1.y, s1.z, s1.w};
    }

    // hv read addrs (t-invariant): lo lanes scatter, hi lanes broadcast zero stripe
    int hvP0[8], hvP1[8];
    #pragma unroll
    for (int kt = 0; kt < 8; ++kt) {
        const int a = lr * 512 + ((kt * 64 + lq * 16 + lr * 64) & 511);
        hvP0[kt] = hi ? 8192 : a;
        hvP1[kt] = hi ? 8192 : a + 4096;
    }
    // h write addrs: all lanes write batch m, their 2 j-chunks
    const int j00 = (4 * w + c0) * 16 + 4 * lq;
    const int j01 = j00 + 16;
    const int w0p0 = m * 512 + ((j00 + m * 64) & 511);
    const int w1p0 = m * 512 + ((j01 + m * 64) & 511);
    const int w0p1 = w0p0 + 4096, w1p1 = w1p0 + 4096;

    const unsigned short* uptr = U3 + ((size_t)(bb * 8 + w) * 64 + l) * 8;
    uint4 uX = *reinterpret_cast<const uint4*>(uptr);
    uptr += 32768;
    uint4 uY;

#define MFMA_I8(W_, H_, A_) __builtin_amdgcn_mfma_i32_16x16x64_i8(W_, H_, A_, 0, 0, 0)

#define RSTEP(P, UC, UN)                                                       \
    {                                                                          \
        UN = *reinterpret_cast<const uint4*>(uptr);                            \
        uptr += 32768;                                                         \
        i32x4 hv[8];                                                           \
        _Pragma("unroll")                                                      \
        for (int kt = 0; kt < 8; ++kt)                                         \
            hv[kt] = *reinterpret_cast<const i32x4*>(h8 + ((P) ? hvP1[kt] : hvP0[kt])); \
        i32x4 a0 = {0,0,0,0}, a1 = {0,0,0,0}, a2 = {0,0,0,0}, a3 = {0,0,0,0};  \
        _Pragma("unroll")                                                      \
        for (int kt = 0; kt < 8; ++kt) {                                       \
            a0 = MFMA_I8(wq[0][kt], hv[kt], a0);                               \
            a1 = MFMA_I8(wq[1][kt], hv[kt], a1);                               \
        }                                                                      \
        _Pragma("unroll")                                                      \
        for (int kt = 0; kt < 8; ++kt) {                                       \
            a2 = MFMA_I8(wq[2][kt], hv[kt], a2);                               \
            a3 = MFMA_I8(wq[3][kt], hv[kt], a3);                               \
        }                                                                      \
        i32x4 b0, b1;                                                          \
        _Pragma("unroll")                                                      \
        for (int r = 0; r < 4; ++r) {                                          \
            const int x2r = __shfl_xor(a2[r], 8);                              \
            const int x3r = __shfl_xor(a3[r], 8);                              \
            b0[r] = hi ? x2r : a0[r];                                          \
            b1[r] = hi ? x3r : a1[r];                                          \
        }                                                                      \
        const unsigned q0 = tq4nr(b0, scA, UC.x, UC.y);                        \
        const unsigned q1 = tq4nr(b1, scB, UC.z, UC.w);                        \
        *reinterpret_cast<unsigned*>(h8 + ((P) ? w0p0 : w0p1)) = q0;           \
        *reinterpret_cast<unsigned*>(h8 + ((P) ? w1p0 : w1p1)) = q1;           \
        __syncthreads();                                                       \
    }

    #pragma unroll 1
    for (int it = 0; it < 1023; ++it) {
        RSTEP(0, uX, uY)     // even t: read par0, write par1
        RSTEP(1, uY, uX)     // odd t
    }
    RSTEP(0, uX, uY)         // t = 2046, prefetches t = 2047 into uY

    // ---- epilogue t = 2047 (read parity 1): precise tanh, f32 store ----
    {
        i32x4 hv[8];
        #pragma unroll
        for (int kt = 0; kt < 8; ++kt)
            hv[kt] = *reinterpret_cast<const i32x4*>(h8 + hvP1[kt]);
        i32x4 a0 = {0,0,0,0}, a1 = {0,0,0,0}, a2 = {0,0,0,0}, a3 = {0,0,0,0};
        #pragma unroll
        for (int kt = 0; kt < 8; ++kt) {
            a0 = MFMA_I8(wq[0][kt], hv[kt], a0);
            a1 = MFMA_I8(wq[1][kt], hv[kt], a1);
            a2 = MFMA_I8(wq[2][kt], hv[kt], a2);
            a3 = MFMA_I8(wq[3][kt], hv[kt], a3);
        }
        i32x4 b0, b1;
        #pragma unroll
        for (int r = 0; r < 4; ++r) {
            const int x2r = __shfl_xor(a2[r], 8);
            const int x3r = __shfl_xor(a3[r], 8);
            b0[r] = hi ? x2r : a0[r];
            b1[r] = hi ? x3r : a1[r];
        }
        float th0[4], th1[4];
        #pragma unroll
        for (int r = 0; r < 4; ++r) {
            const unsigned wd0 = (r < 2) ? uY.x : uY.y;
            const unsigned wd1 = (r < 2) ? uY.z : uY.w;
            const float uf0 = __uint_as_float((r & 1) ? (wd0 & 0xFFFF0000u) : (wd0 << 16));
            const float uf1 = __uint_as_float((r & 1) ? (wd1 & 0xFFFF0000u) : (wd1 << 16));
            const float xa = fmaf((float)b0[r], scA[r], uf0);
            const float xb = fmaf((float)b1[r], scB[r], uf1);
            const float da = __builtin_amdgcn_exp2f(xa) + 1.f;
            const float db = __builtin_amdgcn_exp2f(xb) + 1.f;
            th0[r] = fmaf(__builtin_amdgcn_rcpf(da), -2.f, 1.f);
            th1[r] = fmaf(__builtin_amdgcn_rcpf(db), -2.f, 1.f);
        }
        float* orow = out + (size_t)(bb * 8 + m) * HID;
        *reinterpret_cast<float4*>(orow + j00) = float4{th0[0], th0[1], th0[2], th0[3]};
        *reinterpret_cast<float4*>(orow + j01) = float4{th1[0], th1[1], th1[2], th1[3]};
    }
#undef RSTEP
#undef MFMA_I8
}

// ---------------------------------------------------------------------------
extern "C" void kernel_launch(void* const* d_in, const int* in_sizes, int n_in,
                              void* d_out, int out_size, void* d_ws, size_t ws_size,
                              hipStream_t stream) {
    const float* X   = (const float*)d_in[0];   // [2048][64][300]
    const float* Wih = (const float*)d_in[1];   // [512][300]
    const float* Whh = (const float*)d_in[2];   // [512][512]
    const float* bih = (const float*)d_in[3];   // [512]
    const float* bhh = (const float*)d_in[4];   // [512]
    float* out = (float*)d_out;                 // [64][512]
    unsigned short* U3 = (unsigned short*)d_ws; // 128 MB, m-split rec-lane order

    u_gemm<<<dim3(2048 * 8), dim3(256), 0, stream>>>(X, Wih, bih, bhh, U3);
    rnn_rec<<<dim3(8), dim3(512), 0, stream>>>(Whh, U3, out);
}

// Round 15
// 1654.056 us; speedup vs baseline: 2.2300x; 1.2982x over previous
//
#include <hip/hip_runtime.h>
#include <hip/hip_bf16.h>

#define T_STEPS 2048
#define NB      64
#define IN_DIM  300
#define HID     512

typedef __attribute__((ext_vector_type(8))) short short8;   // 8 bf16 (4 VGPR)
typedef __attribute__((ext_vector_type(4))) float f32x4;    // MFMA f32 accum
typedef __attribute__((ext_vector_type(4))) int   i32x4;    // MFMA i8 frag/accum

#define S2L 2.8853900817779268f          // 2*log2(e): exp(2x) = 2^(x*S2L)

static __device__ __forceinline__ unsigned cvtpk(float lo, float hi) {
    unsigned r;
    asm("v_cvt_pk_bf16_f32 %0, %1, %2" : "=v"(r) : "v"(lo), "v"(hi));
    return r;
}

// tanh+int8-quantize 4 values: x2 = cvt(acc)*sc + u2 (pre-scaled by 2log2e).
// th = 1-2/(2^x2+1); rcp via bit-seed + 1 Newton (R8/R14-verified);
// q = RNE(127*th) via add-magic; pack via v_perm.
static __device__ __forceinline__ unsigned tq4nr(const i32x4 a, const f32x4 s,
                                                 unsigned w0, unsigned w1) {
    unsigned q[4];
    #pragma unroll
    for (int r = 0; r < 4; ++r) {
        const unsigned word = (r < 2) ? w0 : w1;
        const float uf = __uint_as_float((r & 1) ? (word & 0xFFFF0000u) : (word << 16));
        const float x2 = fmaf((float)a[r], s[r], uf);
        const float d = __builtin_amdgcn_exp2f(x2) + 1.f;
        const float r0 = __uint_as_float(0x7EF311C3u - __float_as_uint(d));
        const float rr = r0 * (2.f - d * r0);            // 1 Newton step
        q[r] = __float_as_uint(fmaf(rr, -254.f, 12583039.f));  // byte0 = int8
    }
    return __builtin_amdgcn_perm(
        __builtin_amdgcn_perm(q[3], q[2], 0x0C0C0400u),
        __builtin_amdgcn_perm(q[1], q[0], 0x0C0C0400u), 0x05040100u);
}

// ---------------------------------------------------------------------------
// Kernel 1: U = bf16( (x_t W_ih^T + b_ih + b_hh) * 2log2e ), m=4-split
// rec-lane order: U3[t][bb(16)][wv(8)][lane(64)][r(4)]
//   lane = ((j>>2)&3)*16 + ((j>>4)&3)*4 + (b&3), bb = b>>2, wv = j>>6.
// Staging uses v_cvt_pk_bf16_f32 (4 instr / 8 values, was ~20 f2bf ops).
// XCD-aware block map kept from R14.
// ---------------------------------------------------------------------------
__global__ __launch_bounds__(256, 4) void u_gemm(
    const float* __restrict__ X, const float* __restrict__ Wih,
    const float* __restrict__ bih, const float* __restrict__ bhh,
    unsigned short* __restrict__ U3)
{
    __shared__ unsigned short As[64 * 160];   // X rows (batch m)
    __shared__ unsigned short Bs[64 * 160];   // Wih rows (j)
    const int tid = threadIdx.x;
    const int bxx = blockIdx.x;
    const int xcd_c = bxx & 7, k8 = (bxx >> 3) & 7;
    const int mi = (bxx >> 6) * 8 + xcd_c;    // m-tile (= timestep t), 0..2047
    const int m0 = mi * 64, n0 = k8 * 64;
    const int w = tid >> 6, l = tid & 63;
    const int lq = l >> 4, lr = l & 15;

    const f32x4 zv = {0.f, 0.f, 0.f, 0.f};
    f32x4 acc[2][2] = {{zv, zv}, {zv, zv}};   // [jt][mt]

    for (int kh = 0; kh < 2; ++kh) {
        const int kbase = kh * 160;
        __syncthreads();
        for (int i = tid; i < 64 * 40; i += 256) {
            const int r = i / 40, q = i - r * 40;
            const int kg = kbase + q * 4;
            unsigned int a0 = 0, a1 = 0, b0 = 0, b1 = 0;
            if (kg + 4 <= IN_DIM) {
                const float4 v = *reinterpret_cast<const float4*>(X + (size_t)(m0 + r) * IN_DIM + kg);
                a0 = cvtpk(v.x, v.y);
                a1 = cvtpk(v.z, v.w);
                const float4 u = *reinterpret_cast<const float4*>(Wih + (size_t)(n0 + r) * IN_DIM + kg);
                b0 = cvtpk(u.x, u.y);
                b1 = cvtpk(u.z, u.w);
            }
            int byte = r * 320 + q * 8; byte ^= ((r & 7) << 4);
            *reinterpret_cast<uint2*>(reinterpret_cast<char*>(As) + byte) = make_uint2(a0, a1);
            *reinterpret_cast<uint2*>(reinterpret_cast<char*>(Bs) + byte) = make_uint2(b0, b1);
        }
        __syncthreads();
        #pragma unroll
        for (int kc = 0; kc < 5; ++kc) {
            const int koff = kc * 64 + lq * 16;
            short8 xa[2], wb[2];
            #pragma unroll
            for (int mt = 0; mt < 2; ++mt) {
                const int row = (w >> 1) * 32 + mt * 16 + lr;       // X row (m)
                int abyte = row * 320 + koff; abyte ^= ((row & 7) << 4);
                xa[mt] = *reinterpret_cast<const short8*>(reinterpret_cast<const char*>(As) + abyte);
                const int jrow = (w & 1) * 32 + mt * 16 + lr;       // W row (j)
                int bbyte = jrow * 320 + koff; bbyte ^= ((jrow & 7) << 4);
                wb[mt] = *reinterpret_cast<const short8*>(reinterpret_cast<const char*>(Bs) + bbyte);
            }
            #pragma unroll
            for (int jt = 0; jt < 2; ++jt)
                #pragma unroll
                for (int mt = 0; mt < 2; ++mt)
                    acc[jt][mt] = __builtin_amdgcn_mfma_f32_16x16x32_bf16(
                        wb[jt], xa[mt], acc[jt][mt], 0, 0, 0);
        }
    }
    const int t = mi;
    #pragma unroll
    for (int jt = 0; jt < 2; ++jt) {
        const int jb = n0 + (w & 1) * 32 + jt * 16 + 4 * lq;        // 4 consecutive j
        const float4 b1v = *reinterpret_cast<const float4*>(bih + jb);
        const float4 b2v = *reinterpret_cast<const float4*>(bhh + jb);
        const float4 bv = {(b1v.x + b2v.x) * S2L, (b1v.y + b2v.y) * S2L,
                           (b1v.z + b2v.z) * S2L, (b1v.w + b2v.w) * S2L};
        const int jtg = jb >> 4;                 // j-tile 0..31
        const int wvv = jtg >> 2, qv = jtg & 3;  // wave, chain
        const int lqj = (jb >> 2) & 3;
        #pragma unroll
        for (int mt = 0; mt < 2; ++mt) {
            const int b = (w >> 1) * 32 + mt * 16 + lr;             // batch 0..63
            const int bb = b >> 2, m = b & 3;
            const int lane = lqj * 16 + qv * 4 + m;
            const f32x4 a = acc[jt][mt];
            uint2 p;
            p.x = cvtpk(fmaf(a[0], S2L, bv.x), fmaf(a[1], S2L, bv.y));
            p.y = cvtpk(fmaf(a[2], S2L, bv.z), fmaf(a[3], S2L, bv.w));
            const size_t sidx = ((((size_t)t * 16 + bb) * 8 + wvv) * 64 + lane) * 4;
            *reinterpret_cast<uint2*>(U3 + sidx) = p;
        }
    }
}

// ---------------------------------------------------------------------------
// Kernel 2: int8 recurrence, m=4-SPLIT across 16 CUs (zero communication).
// Block bb owns batches bb*4..bb*4+3, full 512 cols. 256 MFMA/block/step
// (matrix time per CU invariant); B cols hold batches DUPLICATED 4x
// (col = batch col&3) so every lane quartet holds every chain's result:
// lane (q=lr>>2, m=lr&3) selects chain a_q via 12 cndmask (no shuffles) and
// runs ONE tq4nr (4 values). Persistent ZER chain-seed. 1 barrier/step.
// ---------------------------------------------------------------------------
__global__ __launch_bounds__(512) __attribute__((amdgpu_waves_per_eu(2, 2)))
void rnn_rec(const float* __restrict__ Whh, const unsigned short* __restrict__ U3,
             float* __restrict__ out)
{
    const int bb = blockIdx.x;               // 0..15
    const int tid = threadIdx.x;
    const int w = tid >> 6, l = tid & 63;
    const int lq = l >> 4, lr = l & 15;
    const int q = lr >> 2, m = lr & 3;

    __shared__ __align__(16) char h8[2 * 2048];   // [parity][m 4][k 512 rotated]
    __shared__ float wsc_lds[512];                // per-j scale (pre-scaled)

    // ---- one-time: quantize W to registers (wave owns j-tiles 4w..4w+3) ----
    i32x4 wq[4][8];
    #pragma unroll
    for (int c = 0; c < 4; ++c) {
        const float* wr = Whh + (size_t)((4 * w + c) * 16 + lr) * HID;
        float amax = 0.f;
        #pragma unroll
        for (int kt = 0; kt < 8; ++kt) {
            const int k0 = kt * 64 + lq * 16;
            #pragma unroll
            for (int q4 = 0; q4 < 4; ++q4) {
                const float4 v = *reinterpret_cast<const float4*>(wr + k0 + q4 * 4);
                amax = fmaxf(amax, fmaxf(fmaxf(fabsf(v.x), fabsf(v.y)),
                                         fmaxf(fabsf(v.z), fabsf(v.w))));
            }
        }
        amax = fmaxf(amax, __shfl_xor(amax, 16));
        amax = fmaxf(amax, __shfl_xor(amax, 32));    // full-row max
        const float inv = 127.f / amax;
        #pragma unroll
        for (int kt = 0; kt < 8; ++kt) {
            const int k0 = kt * 64 + lq * 16;
            i32x4 pk;
            #pragma unroll
            for (int q4 = 0; q4 < 4; ++q4) {
                const float4 v = *reinterpret_cast<const float4*>(wr + k0 + q4 * 4);
                const int q0 = (int)rintf(v.x * inv), q1 = (int)rintf(v.y * inv);
                const int q2 = (int)rintf(v.z * inv), q3 = (int)rintf(v.w * inv);
                pk[q4] = (q0 & 255) | ((q1 & 255) << 8) | ((q2 & 255) << 16) | (q3 << 24);
            }
            wq[c][kt] = pk;
        }
        if (lq == 0)
            wsc_lds[(4 * w + c) * 16 + lr] = amax * (S2L / 16129.f);
    }
    // ---- h0 = 0 (both parities) ----
    if (tid < 1024) reinterpret_cast<unsigned*>(h8)[tid] = 0;
    __syncthreads();

    // per-lane scale for its chain q: j = (4w+q)*16 + 4lq + r
    f32x4 sc;
    {
        const float4 s0 = *reinterpret_cast<const float4*>(&wsc_lds[(4 * w + q) * 16 + 4 * lq]);
        sc = f32x4{s0.x, s0.y, s0.z, s0.w};
    }
    const bool qb0 = (q & 1) != 0, qb1 = (q & 2) != 0;

    // hv read addrs (t-invariant): col = batch m (4x duplicated), rotated rows
    int hvP0[8], hvP1[8];
    #pragma unroll
    for (int kt = 0; kt < 8; ++kt) {
        const int a = m * 512 + ((kt * 64 + lq * 16 + m * 64) & 511);
        hvP0[kt] = a;
        hvP1[kt] = a + 2048;
    }
    // h write addr: batch m, j-word (4w+q)*16 + 4lq
    const int jby = (4 * w + q) * 16 + 4 * lq;
    const int wp0 = m * 512 + ((jby + m * 64) & 511);
    const int wp1 = wp0 + 2048;

    const unsigned short* uptr = U3 + (((size_t)bb * 8 + w) * 64 + l) * 4;
    uint2 uX = *reinterpret_cast<const uint2*>(uptr);
    uptr += 32768;
    uint2 uY;
    const i32x4 ZER = {0, 0, 0, 0};

#define MFMA_I8(W_, H_, A_) __builtin_amdgcn_mfma_i32_16x16x64_i8(W_, H_, A_, 0, 0, 0)

#define RSTEP(P, UC, UN)                                                       \
    {                                                                          \
        UN = *reinterpret_cast<const uint2*>(uptr);                            \
        uptr += 32768;                                                         \
        i32x4 hv[8];                                                           \
        _Pragma("unroll")                                                      \
        for (int kt = 0; kt < 8; ++kt)                                         \
            hv[kt] = *reinterpret_cast<const i32x4*>(h8 + ((P) ? hvP1[kt] : hvP0[kt])); \
        i32x4 a0 = MFMA_I8(wq[0][0], hv[0], ZER);                              \
        i32x4 a1 = MFMA_I8(wq[1][0], hv[0], ZER);                              \
        _Pragma("unroll")                                                      \
        for (int kt = 1; kt < 8; ++kt) {                                       \
            a0 = MFMA_I8(wq[0][kt], hv[kt], a0);                               \
            a1 = MFMA_I8(wq[1][kt], hv[kt], a1);                               \
        }                                                                      \
        i32x4 a2 = MFMA_I8(wq[2][0], hv[0], ZER);                              \
        i32x4 a3 = MFMA_I8(wq[3][0], hv[0], ZER);                              \
        _Pragma("unroll")                                                      \
        for (int kt = 1; kt < 8; ++kt) {                                       \
            a2 = MFMA_I8(wq[2][kt], hv[kt], a2);                               \
            a3 = MFMA_I8(wq[3][kt], hv[kt], a3);                               \
        }                                                                      \
        i32x4 bsel;                                                            \
        _Pragma("unroll")                                                      \
        for (int r = 0; r < 4; ++r) {                                          \
            const int s01 = qb0 ? a1[r] : a0[r];                               \
            const int s23 = qb0 ? a3[r] : a2[r];                               \
            bsel[r] = qb1 ? s23 : s01;                                         \
        }                                                                      \
        const unsigned qw = tq4nr(bsel, sc, UC.x, UC.y);                       \
        *reinterpret_cast<unsigned*>(h8 + ((P) ? wp0 : wp1)) = qw;             \
        __syncthreads();                                                       \
    }

    #pragma unroll 1
    for (int it = 0; it < 1023; ++it) {
        RSTEP(0, uX, uY)     // even t: read par0, write par1
        RSTEP(1, uY, uX)     // odd t
    }
    RSTEP(0, uX, uY)         // t = 2046, prefetches t = 2047 into uY

    // ---- epilogue t = 2047 (read parity 1): precise tanh, f32 store ----
    {
        i32x4 hv[8];
        #pragma unroll
        for (int kt = 0; kt < 8; ++kt)
            hv[kt] = *reinterpret_cast<const i32x4*>(h8 + hvP1[kt]);
        i32x4 a0 = MFMA_I8(wq[0][0], hv[0], ZER);
        i32x4 a1 = MFMA_I8(wq[1][0], hv[0], ZER);
        i32x4 a2 = MFMA_I8(wq[2][0], hv[0], ZER);
        i32x4 a3 = MFMA_I8(wq[3][0], hv[0], ZER);
        #pragma unroll
        for (int kt = 1; kt < 8; ++kt) {
            a0 = MFMA_I8(wq[0][kt], hv[kt], a0);
            a1 = MFMA_I8(wq[1][kt], hv[kt], a1);
            a2 = MFMA_I8(wq[2][kt], hv[kt], a2);
            a3 = MFMA_I8(wq[3][kt], hv[kt], a3);
        }
        i32x4 bsel;
        #pragma unroll
        for (int r = 0; r < 4; ++r) {
            const int s01 = qb0 ? a1[r] : a0[r];
            const int s23 = qb0 ? a3[r] : a2[r];
            bsel[r] = qb1 ? s23 : s01;
        }
        float th[4];
        #pragma unroll
        for (int r = 0; r < 4; ++r) {
            const unsigned word = (r < 2) ? uY.x : uY.y;
            const float uf = __uint_as_float((r & 1) ? (word & 0xFFFF0000u) : (word << 16));
            const float x2 = fmaf((float)bsel[r], sc[r], uf);
            const float d = __builtin_amdgcn_exp2f(x2) + 1.f;
            th[r] = fmaf(__builtin_amdgcn_rcpf(d), -2.f, 1.f);
        }
        *reinterpret_cast<float4*>(out + (size_t)(bb * 4 + m) * HID + jby) =
            float4{th[0], th[1], th[2], th[3]};
    }
#undef RSTEP
#undef MFMA_I8
}

// ---------------------------------------------------------------------------
extern "C" void kernel_launch(void* const* d_in, const int* in_sizes, int n_in,
                              void* d_out, int out_size, void* d_ws, size_t ws_size,
                              hipStream_t stream) {
    const float* X   = (const float*)d_in[0];   // [2048][64][300]
    const float* Wih = (const float*)d_in[1];   // [512][300]
    const float* Whh = (const float*)d_in[2];   // [512][512]
    const float* bih = (const float*)d_in[3];   // [512]
    const float* bhh = (const float*)d_in[4];   // [512]
    float* out = (float*)d_out;                 // [64][512]
    unsigned short* U3 = (unsigned short*)d_ws; // 128 MB, m=4-split rec-lane order

    u_gemm<<<dim3(2048 * 8), dim3(256), 0, stream>>>(X, Wih, bih, bhh, U3);
    rnn_rec<<<dim3(16), dim3(512), 0, stream>>>(Whh, U3, out);
}